// Round 5
// baseline (507.372 us; speedup 1.0000x reference)
//
#include <hip/hip_runtime.h>

typedef _Float16 half8_t __attribute__((ext_vector_type(8)));
typedef _Float16 half4_t __attribute__((ext_vector_type(4)));

#define NU 100000
#define NI 50000
#define NR (NU + NI)          // unified rows: users then items
#define D 64
#define COARSE 1024
#define RPB 147               // rows per coarse bucket (147*1024 = 150528 >= NR)
#define CAP 8800              // csr LDS staging capacity (bucket mean 6250, sigma ~79; padded +<=441)
#define CHUNK 6144            // placements per block in count/place (fits LDS staging)
#define RPT 6                 // records per thread (CHUNK / 1024)
#define NT4 (NR * 16)         // float4 count of full table
#define PKSLACK 448           // per-bucket slack in pk arrays for mult-of-4 row padding

// out = concat(ue, ie) fp32; curh = same data fp16
__global__ void init_kernel(const float4* __restrict__ ue, const float4* __restrict__ ie,
                            float4* __restrict__ out, half4_t* __restrict__ curh) {
    int idx = blockIdx.x * 256 + threadIdx.x;
    if (idx >= NT4) return;
    float4 v = (idx < NU * 16) ? ue[idx] : ie[idx - NU * 16];
    out[idx] = v;
    half4_t h;
    h[0] = (_Float16)v.x; h[1] = (_Float16)v.y; h[2] = (_Float16)v.z; h[3] = (_Float16)v.w;
    curh[idx] = h;
}

// placement p -> dest row (unified row space, items offset by NU)
__device__ __forceinline__ int place_dest(int p, const int* ui_r, const int* ui_c,
                                          const int* uu_r, const int* ii_r,
                                          int n_ui, int n_uu) {
    if (p < 2 * n_ui) {
        int e = p >> 1;
        return (p & 1) ? NU + ui_c[e] : ui_r[e];
    } else if (p < 2 * n_ui + n_uu) {
        return uu_r[p - 2 * n_ui];
    } else {
        return NU + ii_r[p - 2 * n_ui - n_uu];
    }
}

// per-block coarse histogram -> m[block][COARSE]
__global__ void count_kernel(const int* __restrict__ ui_r, const int* __restrict__ ui_c,
                             const int* __restrict__ uu_r, const int* __restrict__ ii_r,
                             int* __restrict__ m, int n_ui, int n_uu, int nnzt) {
    __shared__ int cnt[COARSE];
    int tid = threadIdx.x;
    cnt[tid] = 0;
    __syncthreads();
    int blk0 = blockIdx.x * CHUNK;
#pragma unroll
    for (int k = 0; k < RPT; k++) {
        int p = blk0 + k * 1024 + tid;
        if (p < nnzt) {
            int dest = place_dest(p, ui_r, ui_c, uu_r, ii_r, n_ui, n_uu);
            atomicAdd(&cnt[dest / RPB], 1);
        }
    }
    __syncthreads();
    m[blockIdx.x * COARSE + tid] = cnt[tid];
}

// one block per coarse bucket: parallel column sum of m -> tots[c]
__global__ void colsum_kernel(const int* __restrict__ m, int* __restrict__ tots, int nblk) {
    __shared__ int s[256];
    int c = blockIdx.x, tid = threadIdx.x;
    int sum = 0;
    for (int b = tid; b < nblk; b += 256) sum += m[b * COARSE + c];
    s[tid] = sum;
    __syncthreads();
    for (int off = 128; off > 0; off >>= 1) {
        if (tid < off) s[tid] += s[tid + off];
        __syncthreads();
    }
    if (tid == 0) tots[c] = s[0];
}

// single block: exclusive scan of tots -> coarse_base
__global__ void scan1_kernel(const int* __restrict__ tots, int* __restrict__ coarse_base) {
    __shared__ int s[COARSE];
    int tid = threadIdx.x;
    int x = tots[tid];
    s[tid] = x;
    __syncthreads();
    for (int off = 1; off < COARSE; off <<= 1) {
        int t = (tid >= off) ? s[tid - off] : 0;
        __syncthreads();
        s[tid] += t;
        __syncthreads();
    }
    coarse_base[tid] = s[tid] - x;
    if (tid == COARSE - 1) coarse_base[COARSE] = s[tid];
}

// one block per coarse bucket: segmented exclusive scan down the column,
// rewriting m in place as absolute per-(block,bucket) base offsets.
__global__ void rebase_kernel(int* __restrict__ m, const int* __restrict__ coarse_base, int nblk) {
    __shared__ int s[256];
    int c = blockIdx.x, tid = threadIdx.x;
    int K = (nblk + 255) / 256;
    int b0 = tid * K;
    int b1 = b0 + K;
    if (b1 > nblk) b1 = nblk;
    int sum = 0;
    for (int b = b0; b < b1; b++) sum += m[b * COARSE + c];
    s[tid] = sum;
    __syncthreads();
    for (int off = 1; off < 256; off <<= 1) {
        int t = (tid >= off) ? s[tid - off] : 0;
        __syncthreads();
        s[tid] += t;
        __syncthreads();
    }
    int run = coarse_base[c] + s[tid] - sum;   // exclusive prefix for this thread's range
    for (int b = b0; b < b1; b++) {
        int v = m[b * COARSE + c];
        m[b * COARSE + c] = run;
        run += v;
    }
}

// LDS-staged bucket sort per block -> fully coalesced scratch writeout.
// record: x = dl<<18 | src ; y = (c<<16) | val_fp16  (csr truncates y to 16 bits)
__global__ void place_kernel(const int* __restrict__ ui_r, const int* __restrict__ ui_c,
                             const float* __restrict__ ui_v,
                             const int* __restrict__ uu_r, const int* __restrict__ uu_c,
                             const float* __restrict__ uu_v,
                             const int* __restrict__ ii_r, const int* __restrict__ ii_c,
                             const float* __restrict__ ii_v,
                             const int* __restrict__ m, uint2* __restrict__ scratch,
                             int n_ui, int n_uu, int nnzt) {
    __shared__ uint2 rec[CHUNK];      // 48 KB
    __shared__ int cnt[COARSE];       // 4 KB
    __shared__ int lbase[COARSE];     // 4 KB
    __shared__ int base_s[COARSE];    // 4 KB
    __shared__ int s_ntot;
    int tid = threadIdx.x;
    cnt[tid] = 0;
    __syncthreads();
    int blk0 = blockIdx.x * CHUNK;
    int rk[RPT];
#pragma unroll
    for (int k = 0; k < RPT; k++) {
        int p = blk0 + k * 1024 + tid;
        rk[k] = -1;
        if (p < nnzt) {
            int dest = place_dest(p, ui_r, ui_c, uu_r, ii_r, n_ui, n_uu);
            int c = dest / RPB;
            int lr = atomicAdd(&cnt[c], 1);   // < 6144 -> 14 bits
            rk[k] = (c << 14) | lr;
        }
    }
    __syncthreads();
    // exclusive scan of cnt -> lbase
    int own = cnt[tid];
    lbase[tid] = own;
    __syncthreads();
    for (int off = 1; off < COARSE; off <<= 1) {
        int t = (tid >= off) ? lbase[tid - off] : 0;
        __syncthreads();
        lbase[tid] += t;
        __syncthreads();
    }
    int incl = lbase[tid];
    __syncthreads();
    lbase[tid] = incl - own;
    if (tid == COARSE - 1) s_ntot = incl;
    base_s[tid] = m[blockIdx.x * COARSE + tid];
    __syncthreads();
    // phase 2: decode records, scatter into LDS grouped by bucket
#pragma unroll
    for (int k = 0; k < RPT; k++) {
        int p = blk0 + k * 1024 + tid;
        if (p >= nnzt) continue;
        int dest, src;
        float v;
        if (p < 2 * n_ui) {
            int e = p >> 1;
            int r = ui_r[e], cc = ui_c[e];
            v = ui_v[e];
            if (p & 1) { dest = NU + cc; src = r; }
            else       { dest = r; src = NU + cc; }
        } else if (p < 2 * n_ui + n_uu) {
            int e = p - 2 * n_ui;
            dest = uu_r[e]; src = uu_c[e]; v = uu_v[e];
        } else {
            int e = p - 2 * n_ui - n_uu;
            dest = NU + ii_r[e]; src = NU + ii_c[e]; v = ii_v[e];
        }
        int c  = rk[k] >> 14;
        int lr = rk[k] & 0x3FFF;
        int dl = dest - c * RPB;                  // < 147
        _Float16 hv = (_Float16)v;
        unsigned short us;
        __builtin_memcpy(&us, &hv, 2);
        rec[lbase[c] + lr] = make_uint2(((unsigned)dl << 18) | (unsigned)src,
                                        ((unsigned)c << 16) | (unsigned)us);
    }
    __syncthreads();
    // phase 3: coalesced streamed writeout
    int ntot = s_ntot;
    for (int i = tid; i < ntot; i += 1024) {
        uint2 r = rec[i];
        int c = r.y >> 16;
        scratch[base_s[c] + (i - lbase[c])] = r;
    }
}

// one block per coarse bucket: fine histogram + scan in LDS, scatter into LDS
// staging, then coalesced writeout. Rows are padded to a multiple of 4 edges
// (pad slots: src=0/val=0) so spmm can use aligned quad loads with no masking.
// pk bucket base: PKB(c) = align4(coarse_base[c]) + c*PKSLACK; gaps zero-filled.
// pk_src holds ROW BYTE OFFSETS (src*128).
__global__ void csr_kernel(const uint2* __restrict__ scratch, const int* __restrict__ coarse_base,
                           int* __restrict__ ptr, int* __restrict__ pk_src,
                           unsigned short* __restrict__ pk_val) {
    __shared__ int s[1024];
    __shared__ int fine[256];            // RPB=147 padded
    __shared__ int fill[256];
    __shared__ int lsrc[CAP];            // 35.2 KB
    __shared__ unsigned short lval[CAP]; // 17.6 KB
    __shared__ int s_pn;
    int c = blockIdx.x, tid = threadIdx.x;
    int rbeg = c * RPB;
    int rcnt = NR - rbeg;
    if (rcnt > RPB) rcnt = RPB;
    if (rcnt < 0) rcnt = 0;
    int base = coarse_base[c], end = coarse_base[c + 1];
    int n = end - base;
    int pkc    = ((base + 3) & ~3) + c * PKSLACK;
    int pknext = ((end  + 3) & ~3) + (c + 1) * PKSLACK;
    if (tid < 256) fine[tid] = 0;
    __syncthreads();
    for (int i = tid; i < n; i += 1024)
        atomicAdd(&fine[scratch[base + i].x >> 18], 1);
    __syncthreads();
    int own = (tid < 256) ? fine[tid] : 0;
    int own4 = (own + 3) & ~3;           // row padded to mult of 4
    s[tid] = own4;
    __syncthreads();
    for (int off = 1; off < 256; off <<= 1) {
        int t = (tid >= off) ? s[tid - off] : 0;
        __syncthreads();
        s[tid] += t;
        __syncthreads();
    }
    int excl4 = s[tid] - own4;
    if (tid < rcnt) ptr[rbeg + tid] = pkc + excl4;
    if (tid == 0 && rbeg + rcnt == NR) ptr[NR] = pknext;   // global CSR end (incl. zero gap)
    if (tid < 256) fill[tid] = excl4;
    if (tid == 255) s_pn = s[255];       // padded bucket size (fine[r]=0 for r>=rcnt)
    __syncthreads();
    int pn = s_pn;
    if (pn <= CAP) {
        for (int i = tid; i < pn; i += 1024) { lsrc[i] = 0; lval[i] = 0; }
        __syncthreads();
        for (int i = tid; i < n; i += 1024) {
            uint2 rec = scratch[base + i];
            int dl = rec.x >> 18;
            int slot = atomicAdd(&fill[dl], 1);
            lsrc[slot] = rec.x & 0x3FFFF;
            lval[slot] = (unsigned short)rec.y;
        }
        __syncthreads();
        for (int i = tid; i < pn; i += 1024) {
            pk_src[pkc + i] = lsrc[i] << 7;   // byte offset: src * 128 (pad slots -> row 0)
            pk_val[pkc + i] = lval[i];
        }
        for (int i = pkc + pn + tid; i < pknext; i += 1024) { pk_src[i] = 0; pk_val[i] = 0; }
    } else {
        // rare overflow path: zero whole padded region, then direct scatter
        for (int i = pkc + tid; i < pknext; i += 1024) { pk_src[i] = 0; pk_val[i] = 0; }
        __syncthreads();
        for (int i = tid; i < n; i += 1024) {
            uint2 rec = scratch[base + i];
            int dl = rec.x >> 18;
            int slot = atomicAdd(&fill[dl], 1);
            pk_src[pkc + slot] = (rec.x & 0x3FFFF) << 7;
            pk_val[pkc + slot] = (unsigned short)rec.y;
        }
    }
}

// 4 rows per wave x 2 groups per row x 8 feature-lanes. Each group strides its
// row's quads by 2 (one int4 + one half4 metadata load + 4 gathers per iter,
// zero masking -- tails handled by exec-mask divergence). Aggregating 4 rows
// per wave cuts ceil-waste: slot utilization ~67% (1 row x 8 groups) -> ~85%.
// Reduce is a single shfl_xor(8) within the 16-lane row-slice; epilogue is
// split across the two groups (g0: fp16 nexth store, g1: fp32 out RMW).
__global__ void spmm_fused(const int* __restrict__ ptr, const int* __restrict__ pk_src,
                           const half4_t* __restrict__ pk_val4,
                           const half8_t* __restrict__ src,
                           half8_t* __restrict__ nexth, float4* __restrict__ out,
                           float final_scale, int store_next) {
    int wave = (int)((blockIdx.x * blockDim.x + threadIdx.x) >> 6);
    int lane = threadIdx.x & 63;
    int sl = lane >> 4;           // row-slice 0..3
    int h  = (lane >> 3) & 1;     // group within slice
    int fl = lane & 7;            // feature lane
    int row = wave * 4 + sl;
    if (row >= NR) return;
    const char* sph = (const char*)src + (fl << 4);
    const int4* ps = (const int4*)pk_src;

    int b = ptr[row], e = ptr[row + 1];
    int q0 = b >> 2, qe = e >> 2;   // b,e are multiples of 4

    float acc[8];
#pragma unroll
    for (int k = 0; k < 8; k++) acc[k] = 0.f;

    for (int q = q0 + h; q < qe; q += 2) {
        int4 sa = ps[q];
        half4_t va = pk_val4[q];
        half8_t x0 = *(const half8_t*)(sph + sa.x);
        half8_t x1 = *(const half8_t*)(sph + sa.y);
        half8_t x2 = *(const half8_t*)(sph + sa.z);
        half8_t x3 = *(const half8_t*)(sph + sa.w);
        float v0 = (float)va[0];
        float v1 = (float)va[1];
        float v2 = (float)va[2];
        float v3 = (float)va[3];
#pragma unroll
        for (int k = 0; k < 8; k++) {
            acc[k] += v0 * (float)x0[k];
            acc[k] += v1 * (float)x1[k];
            acc[k] += v2 * (float)x2[k];
            acc[k] += v3 * (float)x3[k];
        }
    }

    // combine the two groups of this row-slice (lane ^ 8 stays in-slice)
#pragma unroll
    for (int k = 0; k < 8; k++) acc[k] += __shfl_xor(acc[k], 8);

    float hv[8];
#pragma unroll
    for (int k = 0; k < 8; k++) hv[k] = 0.5f * acc[k];

    if (h == 0) {
        if (store_next) {
            half8_t hh;
#pragma unroll
            for (int k = 0; k < 8; k++) hh[k] = (_Float16)hv[k];
            nexth[row * 8 + fl] = hh;
        }
    } else {
        float4* op = out + (size_t)row * 16 + fl * 2;
        float4 o0 = op[0];
        float4 o1 = op[1];
        o0.x = (o0.x + hv[0]) * final_scale;
        o0.y = (o0.y + hv[1]) * final_scale;
        o0.z = (o0.z + hv[2]) * final_scale;
        o0.w = (o0.w + hv[3]) * final_scale;
        o1.x = (o1.x + hv[4]) * final_scale;
        o1.y = (o1.y + hv[5]) * final_scale;
        o1.z = (o1.z + hv[6]) * final_scale;
        o1.w = (o1.w + hv[7]) * final_scale;
        op[0] = o0;
        op[1] = o1;
    }
}

extern "C" void kernel_launch(void* const* d_in, const int* in_sizes, int n_in,
                              void* d_out, int out_size, void* d_ws, size_t ws_size,
                              hipStream_t stream) {
    const float* ue      = (const float*)d_in[0];
    const float* ie      = (const float*)d_in[1];
    const float* uu_val  = (const float*)d_in[2];
    const float* ui_val  = (const float*)d_in[3];
    const float* ii_val  = (const float*)d_in[4];
    const int*   uu_rows = (const int*)d_in[5];
    const int*   uu_cols = (const int*)d_in[6];
    const int*   ui_rows = (const int*)d_in[7];
    const int*   ui_cols = (const int*)d_in[8];
    const int*   ii_rows = (const int*)d_in[9];
    const int*   ii_cols = (const int*)d_in[10];

    const int NNZ_UU = in_sizes[2];
    const int NNZ_UI = in_sizes[3];
    const int NNZ_II = in_sizes[4];
    const int NNZT   = 2 * NNZ_UI + NNZ_UU + NNZ_II;
    const int NBLK   = (NNZT + CHUNK - 1) / CHUNK;
    const int PKTOT  = NNZT + PKSLACK * COARSE + 64;   // padded pk capacity

    float* out = (float*)d_out;

    // ---- workspace layout (16B-aligned blocks first), ~117 MB total ----
    char* wsb = (char*)d_ws;
    half8_t* curh   = (half8_t*)wsb;                         // NR*128 B = 19.2 MB
    uint2*   scratch = (uint2*)(wsb + (size_t)NR * 128);     // NNZT*8 = 51.2 MB
    half8_t* nexth  = (half8_t*)scratch;                     // aliases scratch (dead after csr)
    int*     pk_src = (int*)(scratch + NNZT);                // PKTOT*4 ~ 27.4 MB
    unsigned short* pk_val = (unsigned short*)(pk_src + PKTOT); // PKTOT*2 ~ 13.7 MB
    int*     ptr    = (int*)(pk_val + PKTOT);                // NR+1
    int*     coarse_base = ptr + (NR + 1);                   // COARSE+1
    int*     tots   = coarse_base + (COARSE + 1);            // COARSE
    int*     m      = tots + COARSE;                         // NBLK*COARSE (~4.3 MB)

    init_kernel<<<(NT4 + 255) / 256, 256, 0, stream>>>(
        (const float4*)ue, (const float4*)ie, (float4*)out, (half4_t*)curh);

    count_kernel<<<NBLK, 1024, 0, stream>>>(
        ui_rows, ui_cols, uu_rows, ii_rows, m, NNZ_UI, NNZ_UU, NNZT);

    colsum_kernel<<<COARSE, 256, 0, stream>>>(m, tots, NBLK);
    scan1_kernel<<<1, 1024, 0, stream>>>(tots, coarse_base);
    rebase_kernel<<<COARSE, 256, 0, stream>>>(m, coarse_base, NBLK);

    place_kernel<<<NBLK, 1024, 0, stream>>>(
        ui_rows, ui_cols, ui_val, uu_rows, uu_cols, uu_val,
        ii_rows, ii_cols, ii_val, m, scratch, NNZ_UI, NNZ_UU, NNZT);

    csr_kernel<<<COARSE, 1024, 0, stream>>>(scratch, coarse_base, ptr, pk_src, pk_val);

    int waves = (NR + 3) / 4;                       // 4 rows per wave
    int blocks = (waves * 64 + 511) / 512;          // 8 waves per block

    // layer 1: gather curh -> nexth, out += h
    spmm_fused<<<blocks, 512, 0, stream>>>(
        ptr, pk_src, (const half4_t*)pk_val, curh, nexth, (float4*)out, 1.0f, 1);

    // layer 2: gather nexth, out = (out + h) / 3
    spmm_fused<<<blocks, 512, 0, stream>>>(
        ptr, pk_src, (const half4_t*)pk_val, nexth, curh, (float4*)out, 1.0f / 3.0f, 0);
}

// Round 6
// 472.056 us; speedup vs baseline: 1.0748x; 1.0748x over previous
//
#include <hip/hip_runtime.h>

typedef _Float16 half8_t __attribute__((ext_vector_type(8)));
typedef _Float16 half4_t __attribute__((ext_vector_type(4)));

#define NU 100000
#define NI 50000
#define NR (NU + NI)          // unified rows: users then items
#define D 64
#define COARSE 1024
#define RPB 147               // rows per coarse bucket (147*1024 = 150528 >= NR)
#define CAP 8800              // csr LDS staging capacity (item buckets ~8230+6sigma)
#define CHUNK 6144            // placements per block in count/place (fits LDS staging)
#define RPT 6                 // records per thread (CHUNK / 1024)
#define RPT2 9                // csr cached records per thread (9*1024 >= CAP)
#define NT4 (NR * 16)         // float4 count of full table
#define PKSLACK 448           // per-bucket slack in pk arrays for mult-of-4 row padding

// curh = concat(ue, ie) as fp16. Also zeros the global bucket totals.
// NOTE: no fp32 out write here anymore -- e0 enters the sum in layer 2.
__global__ void init_kernel(const float4* __restrict__ ue, const float4* __restrict__ ie,
                            half4_t* __restrict__ curh, int* __restrict__ tots) {
    int idx = blockIdx.x * 256 + threadIdx.x;
    if (idx < COARSE) tots[idx] = 0;
    if (idx >= NT4) return;
    float4 v = (idx < NU * 16) ? ue[idx] : ie[idx - NU * 16];
    half4_t h;
    h[0] = (_Float16)v.x; h[1] = (_Float16)v.y; h[2] = (_Float16)v.z; h[3] = (_Float16)v.w;
    curh[idx] = h;
}

// placement p -> dest row (unified row space, items offset by NU)
__device__ __forceinline__ int place_dest(int p, const int* ui_r, const int* ui_c,
                                          const int* uu_r, const int* ii_r,
                                          int n_ui, int n_uu) {
    if (p < 2 * n_ui) {
        int e = p >> 1;
        return (p & 1) ? NU + ui_c[e] : ui_r[e];
    } else if (p < 2 * n_ui + n_uu) {
        return uu_r[p - 2 * n_ui];
    } else {
        return NU + ii_r[p - 2 * n_ui - n_uu];
    }
}

// per-block LDS coarse histogram, merged straight into global tots via one
// atomicAdd per (block,bucket). No m matrix, no colsum/rebase kernels.
__global__ void count_kernel(const int* __restrict__ ui_r, const int* __restrict__ ui_c,
                             const int* __restrict__ uu_r, const int* __restrict__ ii_r,
                             int* __restrict__ tots, int n_ui, int n_uu, int nnzt) {
    __shared__ int cnt[COARSE];
    int tid = threadIdx.x;
    cnt[tid] = 0;
    __syncthreads();
    int blk0 = blockIdx.x * CHUNK;
#pragma unroll
    for (int k = 0; k < RPT; k++) {
        int p = blk0 + k * 1024 + tid;
        if (p < nnzt) {
            int dest = place_dest(p, ui_r, ui_c, uu_r, ii_r, n_ui, n_uu);
            atomicAdd(&cnt[dest / RPB], 1);
        }
    }
    __syncthreads();
    if (cnt[tid]) atomicAdd(&tots[tid], cnt[tid]);
}

// single block: exclusive scan of tots -> coarse_base; cursor = coarse_base copy
// (place reserves bucket slots by atomicAdd on cursor; within-bucket order is
// arbitrary, which csr's fine-sort tolerates).
__global__ void scan1_kernel(const int* __restrict__ tots, int* __restrict__ coarse_base,
                             int* __restrict__ cursor) {
    __shared__ int s[COARSE];
    int tid = threadIdx.x;
    int x = tots[tid];
    s[tid] = x;
    __syncthreads();
    for (int off = 1; off < COARSE; off <<= 1) {
        int t = (tid >= off) ? s[tid - off] : 0;
        __syncthreads();
        s[tid] += t;
        __syncthreads();
    }
    int excl = s[tid] - x;
    coarse_base[tid] = excl;
    cursor[tid] = excl;
    if (tid == COARSE - 1) coarse_base[COARSE] = s[tid];
}

// Single-decode LDS-staged bucket sort. Phase 1 decodes each edge FULLY once,
// caching (dl,c,lr) packed + src + val in registers; bucket bases come from an
// atomic cursor reservation (no rebase). Phase 2 scatters from registers.
// record: x = dl<<18 | src ; y = (c<<16) | val_fp16
__global__ void place_kernel(const int* __restrict__ ui_r, const int* __restrict__ ui_c,
                             const float* __restrict__ ui_v,
                             const int* __restrict__ uu_r, const int* __restrict__ uu_c,
                             const float* __restrict__ uu_v,
                             const int* __restrict__ ii_r, const int* __restrict__ ii_c,
                             const float* __restrict__ ii_v,
                             int* __restrict__ cursor, uint2* __restrict__ scratch,
                             int n_ui, int n_uu, int nnzt) {
    __shared__ uint2 rec[CHUNK];      // 48 KB
    __shared__ int cnt[COARSE];       // 4 KB
    __shared__ int lbase[COARSE];     // 4 KB
    __shared__ int base_s[COARSE];    // 4 KB
    __shared__ int s_ntot;
    int tid = threadIdx.x;
    cnt[tid] = 0;
    __syncthreads();
    int blk0 = blockIdx.x * CHUNK;
    unsigned rk[RPT];
    int sk[RPT];
    unsigned short vk[RPT];
#pragma unroll
    for (int k = 0; k < RPT; k++) {
        int p = blk0 + k * 1024 + tid;
        rk[k] = 0xFFFFFFFFu;
        if (p < nnzt) {
            int dest, src;
            float v;
            if (p < 2 * n_ui) {
                int e = p >> 1;
                int r = ui_r[e], cc = ui_c[e];
                v = ui_v[e];
                if (p & 1) { dest = NU + cc; src = r; }
                else       { dest = r; src = NU + cc; }
            } else if (p < 2 * n_ui + n_uu) {
                int e = p - 2 * n_ui;
                dest = uu_r[e]; src = uu_c[e]; v = uu_v[e];
            } else {
                int e = p - 2 * n_ui - n_uu;
                dest = NU + ii_r[e]; src = NU + ii_c[e]; v = ii_v[e];
            }
            int c = dest / RPB;
            int lr = atomicAdd(&cnt[c], 1);       // < 6144 -> 14 bits
            int dl = dest - c * RPB;              // < 147 -> 8 bits
            rk[k] = ((unsigned)dl << 24) | ((unsigned)c << 14) | (unsigned)lr;
            sk[k] = src;
            _Float16 hv = (_Float16)v;
            __builtin_memcpy(&vk[k], &hv, 2);
        }
    }
    __syncthreads();
    int own = cnt[tid];
    if (own) base_s[tid] = atomicAdd(&cursor[tid], own);   // overlap with scan below
    // exclusive scan of cnt -> lbase
    lbase[tid] = own;
    __syncthreads();
    for (int off = 1; off < COARSE; off <<= 1) {
        int t = (tid >= off) ? lbase[tid - off] : 0;
        __syncthreads();
        lbase[tid] += t;
        __syncthreads();
    }
    int incl = lbase[tid];
    __syncthreads();
    lbase[tid] = incl - own;
    if (tid == COARSE - 1) s_ntot = incl;
    __syncthreads();
    // phase 2: scatter records from registers into LDS grouped by bucket
#pragma unroll
    for (int k = 0; k < RPT; k++) {
        if (rk[k] == 0xFFFFFFFFu) continue;
        int c  = (rk[k] >> 14) & 0x3FF;
        int lr = rk[k] & 0x3FFF;
        int dl = rk[k] >> 24;
        rec[lbase[c] + lr] = make_uint2(((unsigned)dl << 18) | (unsigned)sk[k],
                                        ((unsigned)c << 16) | (unsigned)vk[k]);
    }
    __syncthreads();
    // phase 3: coalesced streamed writeout
    int ntot = s_ntot;
    for (int i = tid; i < ntot; i += 1024) {
        uint2 r = rec[i];
        int c = r.y >> 16;
        scratch[base_s[c] + (i - lbase[c])] = r;
    }
}

// one block per coarse bucket: records register-cached on first read (single
// scratch pass), fine histogram + scan, LDS-staged scatter, coalesced writeout.
// Rows padded to mult-of-4 edges (pad: src=0/val=0). pk_src = src byte offsets.
__global__ void csr_kernel(const uint2* __restrict__ scratch, const int* __restrict__ coarse_base,
                           int* __restrict__ ptr, int* __restrict__ pk_src,
                           unsigned short* __restrict__ pk_val) {
    __shared__ int s[1024];
    __shared__ int fine[256];            // RPB=147 padded
    __shared__ int fill[256];
    __shared__ int lsrc[CAP];            // 35.2 KB
    __shared__ unsigned short lval[CAP]; // 17.6 KB
    __shared__ int s_pn;
    int c = blockIdx.x, tid = threadIdx.x;
    int rbeg = c * RPB;
    int rcnt = NR - rbeg;
    if (rcnt > RPB) rcnt = RPB;
    if (rcnt < 0) rcnt = 0;
    int base = coarse_base[c], end = coarse_base[c + 1];
    int n = end - base;
    int pkc    = ((base + 3) & ~3) + c * PKSLACK;
    int pknext = ((end  + 3) & ~3) + (c + 1) * PKSLACK;
    bool small = (n <= RPT2 * 1024);
    if (tid < 256) fine[tid] = 0;
    __syncthreads();
    uint2 rc[RPT2];
    if (small) {
#pragma unroll
        for (int k = 0; k < RPT2; k++) {
            int i = k * 1024 + tid;
            if (i < n) {
                rc[k] = scratch[base + i];
                atomicAdd(&fine[rc[k].x >> 18], 1);
            }
        }
    } else {
        for (int i = tid; i < n; i += 1024)
            atomicAdd(&fine[scratch[base + i].x >> 18], 1);
    }
    __syncthreads();
    int own = (tid < 256) ? fine[tid] : 0;
    int own4 = (own + 3) & ~3;           // row padded to mult of 4
    s[tid] = own4;
    __syncthreads();
    for (int off = 1; off < 256; off <<= 1) {
        int t = (tid >= off) ? s[tid - off] : 0;
        __syncthreads();
        s[tid] += t;
        __syncthreads();
    }
    int excl4 = s[tid] - own4;
    if (tid < rcnt) ptr[rbeg + tid] = pkc + excl4;
    if (tid == 0 && rbeg + rcnt == NR) ptr[NR] = pknext;   // global CSR end
    if (tid < 256) fill[tid] = excl4;
    if (tid == 255) s_pn = s[255];       // padded bucket size
    __syncthreads();
    int pn = s_pn;
    if (small && pn <= CAP) {
        for (int i = tid; i < pn; i += 1024) { lsrc[i] = 0; lval[i] = 0; }
        __syncthreads();
#pragma unroll
        for (int k = 0; k < RPT2; k++) {
            int i = k * 1024 + tid;
            if (i < n) {
                int dl = rc[k].x >> 18;
                int slot = atomicAdd(&fill[dl], 1);
                lsrc[slot] = rc[k].x & 0x3FFFF;
                lval[slot] = (unsigned short)rc[k].y;
            }
        }
        __syncthreads();
        for (int i = tid; i < pn; i += 1024) {
            pk_src[pkc + i] = lsrc[i] << 7;   // byte offset: src * 128 (pads -> row 0)
            pk_val[pkc + i] = lval[i];
        }
        for (int i = pkc + pn + tid; i < pknext; i += 1024) { pk_src[i] = 0; pk_val[i] = 0; }
    } else {
        // rare overflow path: zero whole padded region, then direct scatter
        for (int i = pkc + tid; i < pknext; i += 1024) { pk_src[i] = 0; pk_val[i] = 0; }
        __syncthreads();
        for (int i = tid; i < n; i += 1024) {
            uint2 r2 = scratch[base + i];
            int dl = r2.x >> 18;
            int slot = atomicAdd(&fill[dl], 1);
            pk_src[pkc + slot] = (r2.x & 0x3FFFF) << 7;
            pk_val[pkc + slot] = (unsigned short)r2.y;
        }
    }
}

// Round-4 proven core: one wave per row; 8 edge-groups x 8 feature-lanes; one
// QUAD (4 edges) per group per iteration = 32 edges in flight per wave; quad
// metadata as one int4 + one half4; zero masking (exec-mask tail).
// Epilogue modes: layer 0 writes h1 to out (PURE store, no RMW) + fp16 nexth;
// layer 1 composes out = (h1 + e0 + h2) / 3 reading e0 from the fp32 inputs
// (fp32 add is commutative -> bitwise identical to the old e0-first order).
__global__ void spmm_fused(const int* __restrict__ ptr, const int* __restrict__ pk_src,
                           const half4_t* __restrict__ pk_val4,
                           const half8_t* __restrict__ src,
                           half8_t* __restrict__ nexth, float4* __restrict__ out,
                           const float4* __restrict__ ue4, const float4* __restrict__ ie4,
                           int layer) {
    int w = (int)((blockIdx.x * blockDim.x + threadIdx.x) >> 6);
    int lane = threadIdx.x & 63;
    if (w >= NR) return;
    int g = lane >> 3;
    int fl = lane & 7;
    const char* sph = (const char*)src + (fl << 4);
    const int4* ps = (const int4*)pk_src;

    int b = ptr[w], e = ptr[w + 1];
    int q0 = b >> 2, qe = e >> 2;   // b,e are multiples of 4

    float acc[8];
#pragma unroll
    for (int k = 0; k < 8; k++) acc[k] = 0.f;

    for (int q = q0 + g; q < qe; q += 8) {
        int4 sa = ps[q];
        half4_t va = pk_val4[q];
        half8_t x0 = *(const half8_t*)(sph + sa.x);
        half8_t x1 = *(const half8_t*)(sph + sa.y);
        half8_t x2 = *(const half8_t*)(sph + sa.z);
        half8_t x3 = *(const half8_t*)(sph + sa.w);
        float v0 = (float)va[0];
        float v1 = (float)va[1];
        float v2 = (float)va[2];
        float v3 = (float)va[3];
#pragma unroll
        for (int k = 0; k < 8; k++) {
            acc[k] += v0 * (float)x0[k];
            acc[k] += v1 * (float)x1[k];
            acc[k] += v2 * (float)x2[k];
            acc[k] += v3 * (float)x3[k];
        }
    }

#pragma unroll
    for (int k = 0; k < 8; k++) {
        acc[k] += __shfl_xor(acc[k], 8);
        acc[k] += __shfl_xor(acc[k], 16);
        acc[k] += __shfl_xor(acc[k], 32);
    }

    if (lane < 8) {
        float h[8];
#pragma unroll
        for (int k = 0; k < 8; k++) h[k] = 0.5f * acc[k];
        float4* op = out + (size_t)w * 16 + lane * 2;
        if (layer == 0) {
            half8_t hh;
#pragma unroll
            for (int k = 0; k < 8; k++) hh[k] = (_Float16)h[k];
            nexth[w * 8 + lane] = hh;
            op[0] = make_float4(h[0], h[1], h[2], h[3]);   // out = h1, pure store
            op[1] = make_float4(h[4], h[5], h[6], h[7]);
        } else {
            const float4* ep = (w < NU) ? (ue4 + (size_t)w * 16 + lane * 2)
                                        : (ie4 + (size_t)(w - NU) * 16 + lane * 2);
            const float inv3 = 1.0f / 3.0f;
            float4 o0 = op[0], o1 = op[1];     // = h1 (fp32)
            float4 e0 = ep[0], e1 = ep[1];     // = original embedding
            o0.x = ((o0.x + e0.x) + h[0]) * inv3;
            o0.y = ((o0.y + e0.y) + h[1]) * inv3;
            o0.z = ((o0.z + e0.z) + h[2]) * inv3;
            o0.w = ((o0.w + e0.w) + h[3]) * inv3;
            o1.x = ((o1.x + e1.x) + h[4]) * inv3;
            o1.y = ((o1.y + e1.y) + h[5]) * inv3;
            o1.z = ((o1.z + e1.z) + h[6]) * inv3;
            o1.w = ((o1.w + e1.w) + h[7]) * inv3;
            op[0] = o0;
            op[1] = o1;
        }
    }
}

extern "C" void kernel_launch(void* const* d_in, const int* in_sizes, int n_in,
                              void* d_out, int out_size, void* d_ws, size_t ws_size,
                              hipStream_t stream) {
    const float* ue      = (const float*)d_in[0];
    const float* ie      = (const float*)d_in[1];
    const float* uu_val  = (const float*)d_in[2];
    const float* ui_val  = (const float*)d_in[3];
    const float* ii_val  = (const float*)d_in[4];
    const int*   uu_rows = (const int*)d_in[5];
    const int*   uu_cols = (const int*)d_in[6];
    const int*   ui_rows = (const int*)d_in[7];
    const int*   ui_cols = (const int*)d_in[8];
    const int*   ii_rows = (const int*)d_in[9];
    const int*   ii_cols = (const int*)d_in[10];

    const int NNZ_UU = in_sizes[2];
    const int NNZ_UI = in_sizes[3];
    const int NNZ_II = in_sizes[4];
    const int NNZT   = 2 * NNZ_UI + NNZ_UU + NNZ_II;
    const int NBLK   = (NNZT + CHUNK - 1) / CHUNK;
    const int PKTOT  = NNZT + PKSLACK * COARSE + 64;   // padded pk capacity

    float* out = (float*)d_out;

    // ---- workspace layout (16B-aligned blocks first), ~113 MB total ----
    char* wsb = (char*)d_ws;
    half8_t* curh   = (half8_t*)wsb;                         // NR*128 B = 19.2 MB
    uint2*   scratch = (uint2*)(wsb + (size_t)NR * 128);     // NNZT*8 = 52.4 MB
    half8_t* nexth  = (half8_t*)scratch;                     // aliases scratch (dead after csr)
    int*     pk_src = (int*)(scratch + NNZT);                // PKTOT*4 ~ 27.4 MB
    unsigned short* pk_val = (unsigned short*)(pk_src + PKTOT); // PKTOT*2 ~ 13.7 MB
    int*     ptr    = (int*)(pk_val + PKTOT);                // NR+1
    int*     coarse_base = ptr + (NR + 1);                   // COARSE+1
    int*     tots   = coarse_base + (COARSE + 1);            // COARSE
    int*     cursor = tots + COARSE;                         // COARSE

    init_kernel<<<(NT4 + 255) / 256, 256, 0, stream>>>(
        (const float4*)ue, (const float4*)ie, (half4_t*)curh, tots);

    count_kernel<<<NBLK, 1024, 0, stream>>>(
        ui_rows, ui_cols, uu_rows, ii_rows, tots, NNZ_UI, NNZ_UU, NNZT);

    scan1_kernel<<<1, 1024, 0, stream>>>(tots, coarse_base, cursor);

    place_kernel<<<NBLK, 1024, 0, stream>>>(
        ui_rows, ui_cols, ui_val, uu_rows, uu_cols, uu_val,
        ii_rows, ii_cols, ii_val, cursor, scratch, NNZ_UI, NNZ_UU, NNZT);

    csr_kernel<<<COARSE, 1024, 0, stream>>>(scratch, coarse_base, ptr, pk_src, pk_val);

    int blocks = (NR * 64 + 511) / 512;   // 8 rows per block

    // layer 1: gather curh -> nexth (fp16) + out = h1 (fp32 pure store)
    spmm_fused<<<blocks, 512, 0, stream>>>(
        ptr, pk_src, (const half4_t*)pk_val, curh, nexth, (float4*)out,
        (const float4*)ue, (const float4*)ie, 0);

    // layer 2: gather nexth; out = (h1 + e0 + h2) / 3
    spmm_fused<<<blocks, 512, 0, stream>>>(
        ptr, pk_src, (const half4_t*)pk_val, nexth, curh, (float4*)out,
        (const float4*)ue, (const float4*)ie, 1);
}

// Round 7
// 471.864 us; speedup vs baseline: 1.0752x; 1.0004x over previous
//
#include <hip/hip_runtime.h>

typedef _Float16 half8_t __attribute__((ext_vector_type(8)));
typedef _Float16 half4_t __attribute__((ext_vector_type(4)));

#define NU 100000
#define NI 50000
#define NR (NU + NI)          // unified rows: users then items
#define D 64
#define COARSE 1024
#define RPB 147               // rows per coarse bucket (147*1024 = 150528 >= NR)
#define CAP 8800              // csr LDS staging capacity (item buckets ~8230+6sigma)
#define CHUNK 6144            // placements per block in count/place (fits LDS staging)
#define RPT 6                 // records per thread (CHUNK / 1024)
#define RPT2 9                // csr cached records per thread (9*1024 >= CAP)
#define NT4 (NR * 16)         // float4 count of full table
#define PKSLACK 448           // per-bucket slack in pk arrays for mult-of-4 row padding

// curh = concat(ue, ie) as fp16. Also zeros the global bucket totals.
// NOTE: no fp32 out write here -- e0 enters the sum in layer 2.
__global__ void init_kernel(const float4* __restrict__ ue, const float4* __restrict__ ie,
                            half4_t* __restrict__ curh, int* __restrict__ tots) {
    int idx = blockIdx.x * 256 + threadIdx.x;
    if (idx < COARSE) tots[idx] = 0;
    if (idx >= NT4) return;
    float4 v = (idx < NU * 16) ? ue[idx] : ie[idx - NU * 16];
    half4_t h;
    h[0] = (_Float16)v.x; h[1] = (_Float16)v.y; h[2] = (_Float16)v.z; h[3] = (_Float16)v.w;
    curh[idx] = h;
}

// placement p -> dest row (unified row space, items offset by NU)
__device__ __forceinline__ int place_dest(int p, const int* ui_r, const int* ui_c,
                                          const int* uu_r, const int* ii_r,
                                          int n_ui, int n_uu) {
    if (p < 2 * n_ui) {
        int e = p >> 1;
        return (p & 1) ? NU + ui_c[e] : ui_r[e];
    } else if (p < 2 * n_ui + n_uu) {
        return uu_r[p - 2 * n_ui];
    } else {
        return NU + ii_r[p - 2 * n_ui - n_uu];
    }
}

// per-block LDS coarse histogram, merged straight into global tots via one
// atomicAdd per (block,bucket). No m matrix, no colsum/rebase kernels.
__global__ void count_kernel(const int* __restrict__ ui_r, const int* __restrict__ ui_c,
                             const int* __restrict__ uu_r, const int* __restrict__ ii_r,
                             int* __restrict__ tots, int n_ui, int n_uu, int nnzt) {
    __shared__ int cnt[COARSE];
    int tid = threadIdx.x;
    cnt[tid] = 0;
    __syncthreads();
    int blk0 = blockIdx.x * CHUNK;
#pragma unroll
    for (int k = 0; k < RPT; k++) {
        int p = blk0 + k * 1024 + tid;
        if (p < nnzt) {
            int dest = place_dest(p, ui_r, ui_c, uu_r, ii_r, n_ui, n_uu);
            atomicAdd(&cnt[dest / RPB], 1);
        }
    }
    __syncthreads();
    if (cnt[tid]) atomicAdd(&tots[tid], cnt[tid]);
}

// single block: exclusive scan of tots -> coarse_base; cursor = coarse_base copy
// (place reserves bucket slots by atomicAdd on cursor; within-bucket order is
// arbitrary, which csr's fine-sort tolerates).
__global__ void scan1_kernel(const int* __restrict__ tots, int* __restrict__ coarse_base,
                             int* __restrict__ cursor) {
    __shared__ int s[COARSE];
    int tid = threadIdx.x;
    int x = tots[tid];
    s[tid] = x;
    __syncthreads();
    for (int off = 1; off < COARSE; off <<= 1) {
        int t = (tid >= off) ? s[tid - off] : 0;
        __syncthreads();
        s[tid] += t;
        __syncthreads();
    }
    int excl = s[tid] - x;
    coarse_base[tid] = excl;
    cursor[tid] = excl;
    if (tid == COARSE - 1) coarse_base[COARSE] = s[tid];
}

// Single-decode LDS-staged bucket sort. Phase 1 decodes each edge FULLY once,
// caching (dl,c,lr) packed + src + val in registers; bucket bases come from an
// atomic cursor reservation (no rebase). Phase 2 scatters from registers.
// record: x = dl<<18 | src ; y = (c<<16) | val_fp16
__global__ void place_kernel(const int* __restrict__ ui_r, const int* __restrict__ ui_c,
                             const float* __restrict__ ui_v,
                             const int* __restrict__ uu_r, const int* __restrict__ uu_c,
                             const float* __restrict__ uu_v,
                             const int* __restrict__ ii_r, const int* __restrict__ ii_c,
                             const float* __restrict__ ii_v,
                             int* __restrict__ cursor, uint2* __restrict__ scratch,
                             int n_ui, int n_uu, int nnzt) {
    __shared__ uint2 rec[CHUNK];      // 48 KB
    __shared__ int cnt[COARSE];       // 4 KB
    __shared__ int lbase[COARSE];     // 4 KB
    __shared__ int base_s[COARSE];    // 4 KB
    __shared__ int s_ntot;
    int tid = threadIdx.x;
    cnt[tid] = 0;
    __syncthreads();
    int blk0 = blockIdx.x * CHUNK;
    unsigned rk[RPT];
    int sk[RPT];
    unsigned short vk[RPT];
#pragma unroll
    for (int k = 0; k < RPT; k++) {
        int p = blk0 + k * 1024 + tid;
        rk[k] = 0xFFFFFFFFu;
        if (p < nnzt) {
            int dest, src;
            float v;
            if (p < 2 * n_ui) {
                int e = p >> 1;
                int r = ui_r[e], cc = ui_c[e];
                v = ui_v[e];
                if (p & 1) { dest = NU + cc; src = r; }
                else       { dest = r; src = NU + cc; }
            } else if (p < 2 * n_ui + n_uu) {
                int e = p - 2 * n_ui;
                dest = uu_r[e]; src = uu_c[e]; v = uu_v[e];
            } else {
                int e = p - 2 * n_ui - n_uu;
                dest = NU + ii_r[e]; src = NU + ii_c[e]; v = ii_v[e];
            }
            int c = dest / RPB;
            int lr = atomicAdd(&cnt[c], 1);       // < 6144 -> 14 bits
            int dl = dest - c * RPB;              // < 147 -> 8 bits
            rk[k] = ((unsigned)dl << 24) | ((unsigned)c << 14) | (unsigned)lr;
            sk[k] = src;
            _Float16 hv = (_Float16)v;
            __builtin_memcpy(&vk[k], &hv, 2);
        }
    }
    __syncthreads();
    int own = cnt[tid];
    if (own) base_s[tid] = atomicAdd(&cursor[tid], own);   // overlap with scan below
    // exclusive scan of cnt -> lbase
    lbase[tid] = own;
    __syncthreads();
    for (int off = 1; off < COARSE; off <<= 1) {
        int t = (tid >= off) ? lbase[tid - off] : 0;
        __syncthreads();
        lbase[tid] += t;
        __syncthreads();
    }
    int incl = lbase[tid];
    __syncthreads();
    lbase[tid] = incl - own;
    if (tid == COARSE - 1) s_ntot = incl;
    __syncthreads();
    // phase 2: scatter records from registers into LDS grouped by bucket
#pragma unroll
    for (int k = 0; k < RPT; k++) {
        if (rk[k] == 0xFFFFFFFFu) continue;
        int c  = (rk[k] >> 14) & 0x3FF;
        int lr = rk[k] & 0x3FFF;
        int dl = rk[k] >> 24;
        rec[lbase[c] + lr] = make_uint2(((unsigned)dl << 18) | (unsigned)sk[k],
                                        ((unsigned)c << 16) | (unsigned)vk[k]);
    }
    __syncthreads();
    // phase 3: coalesced streamed writeout
    int ntot = s_ntot;
    for (int i = tid; i < ntot; i += 1024) {
        uint2 r = rec[i];
        int c = r.y >> 16;
        scratch[base_s[c] + (i - lbase[c])] = r;
    }
}

// one block per coarse bucket: records register-cached on first read (single
// scratch pass), fine histogram + scan, LDS-staged scatter, coalesced writeout.
// Rows padded to mult-of-4 edges (pad: src=0/val=0). pk_src = src byte offsets.
__global__ void csr_kernel(const uint2* __restrict__ scratch, const int* __restrict__ coarse_base,
                           int* __restrict__ ptr, int* __restrict__ pk_src,
                           unsigned short* __restrict__ pk_val) {
    __shared__ int s[1024];
    __shared__ int fine[256];            // RPB=147 padded
    __shared__ int fill[256];
    __shared__ int lsrc[CAP];            // 35.2 KB
    __shared__ unsigned short lval[CAP]; // 17.6 KB
    __shared__ int s_pn;
    int c = blockIdx.x, tid = threadIdx.x;
    int rbeg = c * RPB;
    int rcnt = NR - rbeg;
    if (rcnt > RPB) rcnt = RPB;
    if (rcnt < 0) rcnt = 0;
    int base = coarse_base[c], end = coarse_base[c + 1];
    int n = end - base;
    int pkc    = ((base + 3) & ~3) + c * PKSLACK;
    int pknext = ((end  + 3) & ~3) + (c + 1) * PKSLACK;
    bool small = (n <= RPT2 * 1024);
    if (tid < 256) fine[tid] = 0;
    __syncthreads();
    uint2 rc[RPT2];
    if (small) {
#pragma unroll
        for (int k = 0; k < RPT2; k++) {
            int i = k * 1024 + tid;
            if (i < n) {
                rc[k] = scratch[base + i];
                atomicAdd(&fine[rc[k].x >> 18], 1);
            }
        }
    } else {
        for (int i = tid; i < n; i += 1024)
            atomicAdd(&fine[scratch[base + i].x >> 18], 1);
    }
    __syncthreads();
    int own = (tid < 256) ? fine[tid] : 0;
    int own4 = (own + 3) & ~3;           // row padded to mult of 4
    s[tid] = own4;
    __syncthreads();
    for (int off = 1; off < 256; off <<= 1) {
        int t = (tid >= off) ? s[tid - off] : 0;
        __syncthreads();
        s[tid] += t;
        __syncthreads();
    }
    int excl4 = s[tid] - own4;
    if (tid < rcnt) ptr[rbeg + tid] = pkc + excl4;
    if (tid == 0 && rbeg + rcnt == NR) ptr[NR] = pknext;   // global CSR end
    if (tid < 256) fill[tid] = excl4;
    if (tid == 255) s_pn = s[255];       // padded bucket size
    __syncthreads();
    int pn = s_pn;
    if (small && pn <= CAP) {
        for (int i = tid; i < pn; i += 1024) { lsrc[i] = 0; lval[i] = 0; }
        __syncthreads();
#pragma unroll
        for (int k = 0; k < RPT2; k++) {
            int i = k * 1024 + tid;
            if (i < n) {
                int dl = rc[k].x >> 18;
                int slot = atomicAdd(&fill[dl], 1);
                lsrc[slot] = rc[k].x & 0x3FFFF;
                lval[slot] = (unsigned short)rc[k].y;
            }
        }
        __syncthreads();
        for (int i = tid; i < pn; i += 1024) {
            pk_src[pkc + i] = lsrc[i] << 7;   // byte offset: src * 128 (pads -> row 0)
            pk_val[pkc + i] = lval[i];
        }
        for (int i = pkc + pn + tid; i < pknext; i += 1024) { pk_src[i] = 0; pk_val[i] = 0; }
    } else {
        // rare overflow path: zero whole padded region, then direct scatter
        for (int i = pkc + tid; i < pknext; i += 1024) { pk_src[i] = 0; pk_val[i] = 0; }
        __syncthreads();
        for (int i = tid; i < n; i += 1024) {
            uint2 r2 = scratch[base + i];
            int dl = r2.x >> 18;
            int slot = atomicAdd(&fill[dl], 1);
            pk_src[pkc + slot] = (r2.x & 0x3FFFF) << 7;
            pk_val[pkc + slot] = (unsigned short)r2.y;
        }
    }
}

// mixed-precision FMA: acc(f32) += f16(v sel SV) * f16(x sel SX), single
// rounding -- bitwise identical to cvt_f32_f16 + fma. VOP3P, gfx9+.
template<int SV, int SX>
__device__ __forceinline__ void fmamix(float& a, unsigned v, unsigned x) {
    if constexpr (SV == 0 && SX == 0)
        asm("v_fma_mix_f32 %0, %1, %2, %0 op_sel:[0,0,0] op_sel_hi:[1,1,0]"
            : "+v"(a) : "v"(v), "v"(x));
    else if constexpr (SV == 0 && SX == 1)
        asm("v_fma_mix_f32 %0, %1, %2, %0 op_sel:[0,1,0] op_sel_hi:[1,1,0]"
            : "+v"(a) : "v"(v), "v"(x));
    else if constexpr (SV == 1 && SX == 0)
        asm("v_fma_mix_f32 %0, %1, %2, %0 op_sel:[1,0,0] op_sel_hi:[1,1,0]"
            : "+v"(a) : "v"(v), "v"(x));
    else
        asm("v_fma_mix_f32 %0, %1, %2, %0 op_sel:[1,1,0] op_sel_hi:[1,1,0]"
            : "+v"(a) : "v"(v), "v"(x));
}

// one edge's 8 features: value = half SV of vw; x = uint4 of 8 f16
template<int SV>
__device__ __forceinline__ void edge_fma(float (&acc)[8], unsigned vw, const uint4& x) {
    fmamix<SV, 0>(acc[0], vw, x.x);
    fmamix<SV, 1>(acc[1], vw, x.x);
    fmamix<SV, 0>(acc[2], vw, x.y);
    fmamix<SV, 1>(acc[3], vw, x.y);
    fmamix<SV, 0>(acc[4], vw, x.z);
    fmamix<SV, 1>(acc[5], vw, x.z);
    fmamix<SV, 0>(acc[6], vw, x.w);
    fmamix<SV, 1>(acc[7], vw, x.w);
}

// Round-4 proven core: one wave per row; 8 edge-groups x 8 feature-lanes; one
// QUAD (4 edges) per group per iteration = 32 edges in flight per wave; quad
// metadata as one int4 + one uint2; zero masking (exec-mask tail). Inner loop
// is pure v_fma_mix_f32 (no per-element cvt) with uniform-base + 32-bit-offset
// gather addressing (saddr form).
// Epilogue modes: layer 0 writes h1 to out (PURE store, no RMW) + fp16 nexth;
// layer 1 composes out = ((h1 + e0) + h2) / 3 reading e0 from the fp32 inputs.
__global__ void spmm_fused(const int* __restrict__ ptr, const int* __restrict__ pk_src,
                           const uint2* __restrict__ pk_val2,
                           const half8_t* __restrict__ src,
                           half8_t* __restrict__ nexth, float4* __restrict__ out,
                           const float4* __restrict__ ue4, const float4* __restrict__ ie4,
                           int layer) {
    int w = (int)((blockIdx.x * blockDim.x + threadIdx.x) >> 6);
    int lane = threadIdx.x & 63;
    if (w >= NR) return;
    int g = lane >> 3;
    int fl = lane & 7;
    int flo = fl << 4;
    const char* sb = (const char*)src;
    const int4* ps = (const int4*)pk_src;

    int b = ptr[w], e = ptr[w + 1];
    int q0 = b >> 2, qe = e >> 2;   // b,e are multiples of 4

    float acc[8];
#pragma unroll
    for (int k = 0; k < 8; k++) acc[k] = 0.f;

    for (int q = q0 + g; q < qe; q += 8) {
        int4 sa = ps[q];
        uint2 va = pk_val2[q];      // 4 fp16 edge values
        uint4 x0 = *(const uint4*)(sb + (sa.x + flo));
        uint4 x1 = *(const uint4*)(sb + (sa.y + flo));
        uint4 x2 = *(const uint4*)(sb + (sa.z + flo));
        uint4 x3 = *(const uint4*)(sb + (sa.w + flo));
        edge_fma<0>(acc, va.x, x0);
        edge_fma<1>(acc, va.x, x1);
        edge_fma<0>(acc, va.y, x2);
        edge_fma<1>(acc, va.y, x3);
    }

#pragma unroll
    for (int k = 0; k < 8; k++) {
        acc[k] += __shfl_xor(acc[k], 8);
        acc[k] += __shfl_xor(acc[k], 16);
        acc[k] += __shfl_xor(acc[k], 32);
    }

    if (lane < 8) {
        float h[8];
#pragma unroll
        for (int k = 0; k < 8; k++) h[k] = 0.5f * acc[k];
        float4* op = out + (size_t)w * 16 + lane * 2;
        if (layer == 0) {
            half8_t hh;
#pragma unroll
            for (int k = 0; k < 8; k++) hh[k] = (_Float16)h[k];
            nexth[w * 8 + lane] = hh;
            op[0] = make_float4(h[0], h[1], h[2], h[3]);   // out = h1, pure store
            op[1] = make_float4(h[4], h[5], h[6], h[7]);
        } else {
            const float4* ep = (w < NU) ? (ue4 + (size_t)w * 16 + lane * 2)
                                        : (ie4 + (size_t)(w - NU) * 16 + lane * 2);
            const float inv3 = 1.0f / 3.0f;
            float4 o0 = op[0], o1 = op[1];     // = h1 (fp32)
            float4 e0 = ep[0], e1 = ep[1];     // = original embedding
            o0.x = ((o0.x + e0.x) + h[0]) * inv3;
            o0.y = ((o0.y + e0.y) + h[1]) * inv3;
            o0.z = ((o0.z + e0.z) + h[2]) * inv3;
            o0.w = ((o0.w + e0.w) + h[3]) * inv3;
            o1.x = ((o1.x + e1.x) + h[4]) * inv3;
            o1.y = ((o1.y + e1.y) + h[5]) * inv3;
            o1.z = ((o1.z + e1.z) + h[6]) * inv3;
            o1.w = ((o1.w + e1.w) + h[7]) * inv3;
            op[0] = o0;
            op[1] = o1;
        }
    }
}

extern "C" void kernel_launch(void* const* d_in, const int* in_sizes, int n_in,
                              void* d_out, int out_size, void* d_ws, size_t ws_size,
                              hipStream_t stream) {
    const float* ue      = (const float*)d_in[0];
    const float* ie      = (const float*)d_in[1];
    const float* uu_val  = (const float*)d_in[2];
    const float* ui_val  = (const float*)d_in[3];
    const float* ii_val  = (const float*)d_in[4];
    const int*   uu_rows = (const int*)d_in[5];
    const int*   uu_cols = (const int*)d_in[6];
    const int*   ui_rows = (const int*)d_in[7];
    const int*   ui_cols = (const int*)d_in[8];
    const int*   ii_rows = (const int*)d_in[9];
    const int*   ii_cols = (const int*)d_in[10];

    const int NNZ_UU = in_sizes[2];
    const int NNZ_UI = in_sizes[3];
    const int NNZ_II = in_sizes[4];
    const int NNZT   = 2 * NNZ_UI + NNZ_UU + NNZ_II;
    const int NBLK   = (NNZT + CHUNK - 1) / CHUNK;
    const int PKTOT  = NNZT + PKSLACK * COARSE + 64;   // padded pk capacity

    float* out = (float*)d_out;

    // ---- workspace layout (16B-aligned blocks first), ~113 MB total ----
    char* wsb = (char*)d_ws;
    half8_t* curh   = (half8_t*)wsb;                         // NR*128 B = 19.2 MB
    uint2*   scratch = (uint2*)(wsb + (size_t)NR * 128);     // NNZT*8 = 52.4 MB
    half8_t* nexth  = (half8_t*)scratch;                     // aliases scratch (dead after csr)
    int*     pk_src = (int*)(scratch + NNZT);                // PKTOT*4 ~ 27.4 MB
    unsigned short* pk_val = (unsigned short*)(pk_src + PKTOT); // PKTOT*2 ~ 13.7 MB
    int*     ptr    = (int*)(pk_val + PKTOT);                // NR+1
    int*     coarse_base = ptr + (NR + 1);                   // COARSE+1
    int*     tots   = coarse_base + (COARSE + 1);            // COARSE
    int*     cursor = tots + COARSE;                         // COARSE

    init_kernel<<<(NT4 + 255) / 256, 256, 0, stream>>>(
        (const float4*)ue, (const float4*)ie, (half4_t*)curh, tots);

    count_kernel<<<NBLK, 1024, 0, stream>>>(
        ui_rows, ui_cols, uu_rows, ii_rows, tots, NNZ_UI, NNZ_UU, NNZT);

    scan1_kernel<<<1, 1024, 0, stream>>>(tots, coarse_base, cursor);

    place_kernel<<<NBLK, 1024, 0, stream>>>(
        ui_rows, ui_cols, ui_val, uu_rows, uu_cols, uu_val,
        ii_rows, ii_cols, ii_val, cursor, scratch, NNZ_UI, NNZ_UU, NNZT);

    csr_kernel<<<COARSE, 1024, 0, stream>>>(scratch, coarse_base, ptr, pk_src, pk_val);

    int blocks = (NR * 64 + 511) / 512;   // 8 rows per block

    // layer 1: gather curh -> nexth (fp16) + out = h1 (fp32 pure store)
    spmm_fused<<<blocks, 512, 0, stream>>>(
        ptr, pk_src, (const uint2*)pk_val, curh, nexth, (float4*)out,
        (const float4*)ue, (const float4*)ie, 0);

    // layer 2: gather nexth; out = (h1 + e0 + h2) / 3
    spmm_fused<<<blocks, 512, 0, stream>>>(
        ptr, pk_src, (const uint2*)pk_val, nexth, curh, (float4*)out,
        (const float4*)ue, (const float4*)ie, 1);
}